// Round 3
// baseline (103.553 us; speedup 1.0000x reference)
//
#include <hip/hip_runtime.h>
#include <hip/hip_bf16.h>

#define N_ROWS 8192
#define DIM    128
#define NCHUNK 32                  // column chunks in sim kernel
#define CHUNKC (N_ROWS / NCHUNK)   // 256 cols per chunk
#define NT     (CHUNKC / 32)       // 8 tiles per chunk

// sqrt(2*log2(e)) : (s*a)·(s*b) = 2*log2(e)*a·b, so exp2(dot) = exp(2*sim)
#define ENSCALE 1.6986436f

typedef __attribute__((ext_vector_type(8)))  short short8;
typedef __attribute__((ext_vector_type(16))) float f32x16;

__device__ inline unsigned short f2bf(float f) {
    unsigned u = __float_as_uint(f);
    unsigned r = (u + 0x7FFFu + ((u >> 16) & 1u)) >> 16;
    return (unsigned short)r;
}

__device__ inline int labof(int4 v, int j) {
    return j == 0 ? v.x : j == 1 ? v.y : j == 2 ? v.z : v.w;
}

// Kernel 1: per-row L2 normalize embed -> bf16 (scaled by ENSCALE), and
// e2p[i] = exp(2*dot(en,pn)) in fp32.
__global__ __launch_bounds__(256) void norm_kernel(
    const float* __restrict__ embed, const float* __restrict__ proxy,
    short* __restrict__ enb, float* __restrict__ e2p)
{
    int wave = threadIdx.x >> 6, lane = threadIdx.x & 63;
    int row = blockIdx.x * 4 + wave;

    const float2 ev = *(const float2*)(embed + row * DIM + lane * 2);
    float ss = ev.x * ev.x + ev.y * ev.y;
#pragma unroll
    for (int m = 1; m < 64; m <<= 1) ss += __shfl_xor(ss, m, 64);
    float inv_e = 1.0f / fmaxf(sqrtf(ss), 1e-8f);
    float ex = ev.x * inv_e, ey = ev.y * inv_e;

    const float2 pv = *(const float2*)(proxy + row * DIM + lane * 2);
    float ps = pv.x * pv.x + pv.y * pv.y;
#pragma unroll
    for (int m = 1; m < 64; m <<= 1) ps += __shfl_xor(ps, m, 64);
    float inv_p = 1.0f / fmaxf(sqrtf(ps), 1e-8f);

    float dot = ex * (pv.x * inv_p) + ey * (pv.y * inv_p);
#pragma unroll
    for (int m = 1; m < 64; m <<= 1) dot += __shfl_xor(dot, m, 64);

    ushort2 st; st.x = f2bf(ex * ENSCALE); st.y = f2bf(ey * ENSCALE);
    *(ushort2*)(enb + row * DIM + lane * 2) = st;
    if (lane == 0) e2p[row] = __expf(2.0f * dot);
}

// Kernel 2: fused sim-GEMM (32x32x16 MFMA) + exp + masked row sums.
// Operand-swapped: c = mfma(B_cols, A_rows, c) so output lane cl owns row
// wrbase+cl and the 16 acc regs span the 32 columns of the tile:
//   col_in_tile(reg) = (reg&3) + 4*hi + 8*(reg>>2),  row = lane&31.
// 2-deep ping-pong prefetch of column fragments + column labels.
#define LOADCOLS(cb, bf, lb)                                                   \
    {                                                                          \
        const short* brow_ = enb + (size_t)((cb) + cl) * DIM + hi * 8;         \
        _Pragma("unroll")                                                      \
        for (int kk = 0; kk < 8; kk++)                                         \
            bf[kk] = *(const short8*)(brow_ + kk * 16);                        \
        _Pragma("unroll")                                                      \
        for (int q = 0; q < 4; q++)                                            \
            lb[q] = *(const int4*)(label + (cb) + 8 * q + 4 * hi);             \
    }

#define COMPUTE(cb, bf, lb)                                                    \
    {                                                                          \
        f32x16 c = {};                                                         \
        _Pragma("unroll")                                                      \
        for (int kk = 0; kk < 8; kk++)                                         \
            c = __builtin_amdgcn_mfma_f32_32x32x16_bf16(bf[kk], rres[kk], c,   \
                                                        0, 0, 0);              \
        float s[16], psv[16];                                                  \
        _Pragma("unroll")                                                      \
        for (int reg = 0; reg < 16; reg++)                                     \
            s[reg] = __builtin_amdgcn_exp2f(c[reg]);                           \
        if ((cb) == wrbase) {                                                  \
            _Pragma("unroll")                                                  \
            for (int reg = 0; reg < 16; reg++) {                               \
                int m_ = (reg & 3) + 4 * hi + 8 * (reg >> 2);                  \
                s[reg] = (m_ == cl) ? 0.f : s[reg];                            \
            }                                                                  \
        }                                                                      \
        _Pragma("unroll")                                                      \
        for (int reg = 0; reg < 16; reg++)                                     \
            psv[reg] = (labof(lb[reg >> 2], reg & 3) == rlab) ? s[reg] : 0.f;  \
        _Pragma("unroll")                                                      \
        for (int st = 1; st < 16; st <<= 1)                                    \
            for (int i = 0; i < 16; i += 2 * st) {                             \
                s[i] += s[i + st];                                             \
                psv[i] += psv[i + st];                                         \
            }                                                                  \
        tot += s[0];                                                           \
        pos += psv[0];                                                         \
    }

__global__ __launch_bounds__(256) void simsum_kernel(
    const short* __restrict__ enb, const int* __restrict__ label,
    float* __restrict__ ptot, float* __restrict__ ppos)
{
    const int wave = threadIdx.x >> 6, lane = threadIdx.x & 63;
    const int cl = lane & 31;       // output row lane
    const int hi = lane >> 5;       // k-group
    const int wrbase = blockIdx.x * 128 + wave * 32;   // wave's first row

    // resident fragment: wave's own 32 rows (used as the B operand)
    short8 rres[8];
    const short* arow = enb + (size_t)(wrbase + cl) * DIM + hi * 8;
#pragma unroll
    for (int kk = 0; kk < 8; kk++)
        rres[kk] = *(const short8*)(arow + kk * 16);
    const int rlab = label[wrbase + cl];

    float tot = 0.f, pos = 0.f;
    const int cbase0 = blockIdx.y * CHUNKC;

    short8 bA[8], bB[8];
    int4 lA[4], lB[4];

    LOADCOLS(cbase0, bA, lA);
#pragma unroll 1
    for (int t = 0; t < NT; t += 2) {
        LOADCOLS(cbase0 + (t + 1) * 32, bB, lB);
        COMPUTE(cbase0 + t * 32, bA, lA);
        if (t + 2 < NT) {
            LOADCOLS(cbase0 + (t + 2) * 32, bA, lA);
        }
        COMPUTE(cbase0 + (t + 1) * 32, bB, lB);
    }

    // merge the two k-groups (same row, disjoint columns)
    tot += __shfl_xor(tot, 32, 64);
    pos += __shfl_xor(pos, 32, 64);
    if (hi == 0) {
        ptot[blockIdx.y * N_ROWS + wrbase + cl] = tot;
        ppos[blockIdx.y * N_ROWS + wrbase + cl] = pos;
    }
}

// Kernel 3a: per-row log-ratio, block partial sums.
__global__ __launch_bounds__(256) void loss_partial_kernel(
    const float* __restrict__ e2p, const float* __restrict__ ptot,
    const float* __restrict__ ppos, float* __restrict__ pl)
{
    int i = blockIdx.x * 256 + threadIdx.x;
    float tot = 0.f, pos = 0.f;
#pragma unroll
    for (int c = 0; c < NCHUNK; c++) {
        tot += ptot[c * N_ROWS + i];
        pos += ppos[c * N_ROWS + i];
    }
    float e = e2p[i];
    float v = __logf((e + pos) / (e + tot));
#pragma unroll
    for (int m = 1; m < 64; m <<= 1) v += __shfl_xor(v, m, 64);
    __shared__ float red[4];
    int wave = threadIdx.x >> 6, lane = threadIdx.x & 63;
    if (lane == 0) red[wave] = v;
    __syncthreads();
    if (threadIdx.x == 0) pl[blockIdx.x] = red[0] + red[1] + red[2] + red[3];
}

// Kernel 3b: final sum of 32 partials -> -mean
__global__ void loss_final_kernel(const float* __restrict__ pl,
                                  float* __restrict__ out)
{
    float v = (threadIdx.x < 32) ? pl[threadIdx.x] : 0.f;
#pragma unroll
    for (int m = 1; m < 64; m <<= 1) v += __shfl_xor(v, m, 64);
    if (threadIdx.x == 0) out[0] = -v / (float)N_ROWS;
}

extern "C" void kernel_launch(void* const* d_in, const int* in_sizes, int n_in,
                              void* d_out, int out_size, void* d_ws, size_t ws_size,
                              hipStream_t stream) {
    const float* embed = (const float*)d_in[0];
    const float* proxy = (const float*)d_in[1];
    const int*   label = (const int*)d_in[2];
    float* out = (float*)d_out;

    char* ws = (char*)d_ws;
    short* enb = (short*)ws;                                    // 2 MB
    float* e2p = (float*)(ws + 2u * N_ROWS * DIM);              // 32 KB
    float* ptot = e2p + N_ROWS;                                 // 1 MB
    float* ppos = ptot + NCHUNK * N_ROWS;                       // 1 MB
    float* pl   = ppos + NCHUNK * N_ROWS;                       // 128 B

    hipLaunchKernelGGL(norm_kernel, dim3(N_ROWS / 4), dim3(256), 0, stream,
                       embed, proxy, enb, e2p);
    hipLaunchKernelGGL(simsum_kernel, dim3(N_ROWS / 128, NCHUNK), dim3(256), 0, stream,
                       enb, label, ptot, ppos);
    hipLaunchKernelGGL(loss_partial_kernel, dim3(N_ROWS / 256), dim3(256), 0, stream,
                       e2p, ptot, ppos, pl);
    hipLaunchKernelGGL(loss_final_kernel, dim3(1), dim3(64), 0, stream, pl, out);
}

// Round 4
// 59.138 us; speedup vs baseline: 1.7510x; 1.7510x over previous
//
#include <hip/hip_runtime.h>
#include <hip/hip_bf16.h>

#define N_ROWS 8192
#define DIM    128
#define NCHUNK 16                  // column chunks in sim kernel
#define CHUNKC (N_ROWS / NCHUNK)   // 512 cols per chunk
#define NT     (CHUNKC / 32)       // 16 tiles of 32 cols per chunk

// sqrt(2*log2(e)) : (s*a)·(s*b) = 2*log2(e)*a·b, so exp2(dot) = exp(2*sim)
#define ENSCALE 1.6986436f

typedef __attribute__((ext_vector_type(8)))  short short8;
typedef __attribute__((ext_vector_type(16))) float f32x16;
typedef __attribute__((address_space(3))) void lds_void;
typedef const __attribute__((address_space(1))) void g_void;

__device__ inline unsigned short f2bf(float f) {
    unsigned u = __float_as_uint(f);
    unsigned r = (u + 0x7FFFu + ((u >> 16) & 1u)) >> 16;
    return (unsigned short)r;
}
__device__ inline float bf2f(unsigned short u) {
    return __uint_as_float(((unsigned)u) << 16);
}

// Kernel 1: per-row L2 normalize embed -> bf16 (scaled by ENSCALE), and
// e2p[i] = exp(2*dot(en,pn)) in fp32.
__global__ __launch_bounds__(256) void norm_kernel(
    const float* __restrict__ embed, const float* __restrict__ proxy,
    short* __restrict__ enb, float* __restrict__ e2p)
{
    int wave = threadIdx.x >> 6, lane = threadIdx.x & 63;
    int row = blockIdx.x * 4 + wave;

    const float2 ev = *(const float2*)(embed + row * DIM + lane * 2);
    float ss = ev.x * ev.x + ev.y * ev.y;
#pragma unroll
    for (int m = 1; m < 64; m <<= 1) ss += __shfl_xor(ss, m, 64);
    float inv_e = 1.0f / fmaxf(sqrtf(ss), 1e-8f);
    float ex = ev.x * inv_e, ey = ev.y * inv_e;

    const float2 pv = *(const float2*)(proxy + row * DIM + lane * 2);
    float ps = pv.x * pv.x + pv.y * pv.y;
#pragma unroll
    for (int m = 1; m < 64; m <<= 1) ps += __shfl_xor(ps, m, 64);
    float inv_p = 1.0f / fmaxf(sqrtf(ps), 1e-8f);

    float dot = ex * (pv.x * inv_p) + ey * (pv.y * inv_p);
#pragma unroll
    for (int m = 1; m < 64; m <<= 1) dot += __shfl_xor(dot, m, 64);

    ushort2 st; st.x = f2bf(ex * ENSCALE); st.y = f2bf(ey * ENSCALE);
    *(ushort2*)(enb + row * DIM + lane * 2) = st;
    if (lane == 0) e2p[row] = __expf(2.0f * dot);
}

// Kernel 2: fused sim-GEMM + exp + full row sum (tot only; pos is separate).
// 2-phase LDS pipeline: block stages a 32-col x 128-dim bf16 tile (8KB) into
// LDS (double-buffered) via global_load_lds(16B); all 4 waves consume it.
// XOR swizzle (both sides): LDS byte B holds global chunk j^(c&15) of col c,
// where c = B>>8, j = (B>>4)&15. Read applies the same XOR -> b128-floor banks.
// Operand-swapped MFMA: lane owns output row wrbase+cl; regs span tile cols.
__global__ __launch_bounds__(256, 4) void simsum_kernel(
    const short* __restrict__ enb, float* __restrict__ ptot)
{
    __shared__ __align__(16) char lds[2 * 8192];
    const int tid = threadIdx.x;
    const int wave = tid >> 6, lane = tid & 63;
    const int cl = lane & 31;       // output row lane
    const int hi = lane >> 5;       // k-group
    const int wrbase = blockIdx.x * 128 + wave * 32;
    const int cbase0 = blockIdx.y * CHUNKC;

    // staging source indices (fixed per thread)
    const int sc = tid >> 4;                 // 0..15 (col within half-tile)
    const int sj = (tid & 15) ^ sc;          // pre-swizzled global chunk

    auto stage = [&](int buf, int cb) {
        const short* s0 = enb + (size_t)(cb + sc) * DIM + sj * 8;
        const short* s1 = enb + (size_t)(cb + 16 + sc) * DIM + sj * 8;
        char* d0 = lds + buf * 8192 + wave * 1024;          // wave-uniform
        char* d1 = d0 + 4096;
        __builtin_amdgcn_global_load_lds((g_void*)s0, (lds_void*)d0, 16, 0, 0);
        __builtin_amdgcn_global_load_lds((g_void*)s1, (lds_void*)d1, 16, 0, 0);
    };

    // resident fragment: wave's own 32 rows (B operand of the swapped MFMA)
    short8 rres[8];
    const short* arow = enb + (size_t)(wrbase + cl) * DIM + hi * 8;
#pragma unroll
    for (int kk = 0; kk < 8; kk++)
        rres[kk] = *(const short8*)(arow + kk * 16);

    float tot[16];
#pragma unroll
    for (int r = 0; r < 16; r++) tot[r] = 0.f;

    int cur = 0;
    stage(0, cbase0);
    __syncthreads();

#pragma unroll 1
    for (int t = 0; t < NT; t++) {
        if (t + 1 < NT) stage(cur ^ 1, cbase0 + (t + 1) * 32);

        // read this lane's column fragments (swizzled offsets)
        const char* base = lds + cur * 8192 + cl * 256;
        short8 b[8];
#pragma unroll
        for (int kk = 0; kk < 8; kk++) {
            int off = ((kk * 2 + hi) ^ (cl & 15)) * 16;
            b[kk] = *(const short8*)(base + off);
        }

        f32x16 c = {};
#pragma unroll
        for (int kk = 0; kk < 8; kk++)
            c = __builtin_amdgcn_mfma_f32_32x32x16_bf16(b[kk], rres[kk], c, 0, 0, 0);

        const int cb = cbase0 + t * 32;
        if (cb == wrbase) {       // diagonal tile: mask col == row
#pragma unroll
            for (int r = 0; r < 16; r++) {
                int colr = (r & 3) + 4 * hi + 8 * (r >> 2);
                float s = __builtin_amdgcn_exp2f(c[r]);
                tot[r] += (colr == cl) ? 0.f : s;
            }
        } else {
#pragma unroll
            for (int r = 0; r < 16; r++)
                tot[r] += __builtin_amdgcn_exp2f(c[r]);
        }

        __syncthreads();          // drains vmcnt(0): next buffer is ready
        cur ^= 1;
    }

    float s = 0.f;
#pragma unroll
    for (int r = 0; r < 16; r++) s += tot[r];
    s += __shfl_xor(s, 32, 64);   // merge the two k-groups (disjoint cols)
    if (hi == 0)
        ptot[blockIdx.y * N_ROWS + wrbase + cl] = s;
}

// Kernel 3: positives. One wave per row: ballot-scan labels, lane-parallel
// dot for each same-label j (avg ~8 per row), accumulate exp2(dot_scaled).
__global__ __launch_bounds__(256) void pos_kernel(
    const short* __restrict__ enb, const int* __restrict__ label,
    float* __restrict__ posr)
{
    int wave = threadIdx.x >> 6, lane = threadIdx.x & 63;
    int row = blockIdx.x * 4 + wave;
    int mylab = label[row];

    ushort2 e2 = *(const ushort2*)(enb + (size_t)row * DIM + lane * 2);
    float ei0 = bf2f(e2.x), ei1 = bf2f(e2.y);

    float acc = 0.f;
    for (int ch = 0; ch < N_ROWS / 64; ch++) {
        int j = ch * 64 + lane;
        bool m = (label[j] == mylab) && (j != row);
        unsigned long long mask = __ballot(m);
        while (mask) {
            int jj = ch * 64 + (__ffsll(mask) - 1);
            mask &= mask - 1;
            ushort2 f2 = *(const ushort2*)(enb + (size_t)jj * DIM + lane * 2);
            float d = ei0 * bf2f(f2.x) + ei1 * bf2f(f2.y);
#pragma unroll
            for (int s = 1; s < 64; s <<= 1) d += __shfl_xor(d, s, 64);
            acc += __builtin_amdgcn_exp2f(d);
        }
    }
    if (lane == 0) posr[row] = acc;
}

// Kernel 4: per-row log-ratio, block partial sums.
__global__ __launch_bounds__(256) void loss_partial_kernel(
    const float* __restrict__ e2p, const float* __restrict__ ptot,
    const float* __restrict__ posr, float* __restrict__ pl)
{
    int i = blockIdx.x * 256 + threadIdx.x;
    float tot = 0.f;
#pragma unroll
    for (int c = 0; c < NCHUNK; c++) tot += ptot[c * N_ROWS + i];
    float e = e2p[i];
    float v = __logf((e + posr[i]) / (e + tot));
#pragma unroll
    for (int m = 1; m < 64; m <<= 1) v += __shfl_xor(v, m, 64);
    __shared__ float red[4];
    int wave = threadIdx.x >> 6, lane = threadIdx.x & 63;
    if (lane == 0) red[wave] = v;
    __syncthreads();
    if (threadIdx.x == 0) pl[blockIdx.x] = red[0] + red[1] + red[2] + red[3];
}

// Kernel 5: final sum of 32 partials -> -mean
__global__ void loss_final_kernel(const float* __restrict__ pl,
                                  float* __restrict__ out)
{
    float v = (threadIdx.x < 32) ? pl[threadIdx.x] : 0.f;
#pragma unroll
    for (int m = 1; m < 64; m <<= 1) v += __shfl_xor(v, m, 64);
    if (threadIdx.x == 0) out[0] = -v / (float)N_ROWS;
}

extern "C" void kernel_launch(void* const* d_in, const int* in_sizes, int n_in,
                              void* d_out, int out_size, void* d_ws, size_t ws_size,
                              hipStream_t stream) {
    const float* embed = (const float*)d_in[0];
    const float* proxy = (const float*)d_in[1];
    const int*   label = (const int*)d_in[2];
    float* out = (float*)d_out;

    char* ws = (char*)d_ws;
    short* enb  = (short*)ws;                                   // 2 MB
    float* e2p  = (float*)(ws + 2u * N_ROWS * DIM);             // 32 KB
    float* ptot = e2p + N_ROWS;                                 // 512 KB
    float* posr = ptot + NCHUNK * N_ROWS;                       // 32 KB
    float* pl   = posr + N_ROWS;                                // 128 B

    hipLaunchKernelGGL(norm_kernel, dim3(N_ROWS / 4), dim3(256), 0, stream,
                       embed, proxy, enb, e2p);
    hipLaunchKernelGGL(simsum_kernel, dim3(N_ROWS / 128, NCHUNK), dim3(256), 0, stream,
                       enb, ptot);
    hipLaunchKernelGGL(pos_kernel, dim3(N_ROWS / 4), dim3(256), 0, stream,
                       enb, label, posr);
    hipLaunchKernelGGL(loss_partial_kernel, dim3(N_ROWS / 256), dim3(256), 0, stream,
                       e2p, ptot, posr, pl);
    hipLaunchKernelGGL(loss_final_kernel, dim3(1), dim3(64), 0, stream, pl, out);
}

// Round 5
// 57.730 us; speedup vs baseline: 1.7937x; 1.0244x over previous
//
#include <hip/hip_runtime.h>
#include <hip/hip_bf16.h>

#define N_ROWS 8192
#define DIM    128
#define NCHUNK 16                  // column chunks in sim kernel
#define CHUNKC (N_ROWS / NCHUNK)   // 512 cols per chunk
#define NT     (CHUNKC / 32)       // 16 tiles of 32 cols per chunk
#define NPH    (NT / 2)            // 8 phases, 2 tiles per phase

// sqrt(2*log2(e)) : (s*a)·(s*b) = 2*log2(e)*a·b, so exp2(dot) = exp(2*sim)
#define ENSCALE 1.6986436f

typedef __attribute__((ext_vector_type(8)))  short short8;
typedef __attribute__((ext_vector_type(16))) float f32x16;
typedef __attribute__((address_space(3))) void lds_void;
typedef const __attribute__((address_space(1))) void g_void;

__device__ inline unsigned short f2bf(float f) {
    unsigned u = __float_as_uint(f);
    unsigned r = (u + 0x7FFFu + ((u >> 16) & 1u)) >> 16;
    return (unsigned short)r;
}
__device__ inline float bf2f(unsigned short u) {
    return __uint_as_float(((unsigned)u) << 16);
}

// Kernel 1: per-row L2 normalize embed -> bf16 (scaled by ENSCALE), and
// e2p[i] = exp(2*dot(en,pn)) in fp32.
__global__ __launch_bounds__(256) void norm_kernel(
    const float* __restrict__ embed, const float* __restrict__ proxy,
    short* __restrict__ enb, float* __restrict__ e2p)
{
    int wave = threadIdx.x >> 6, lane = threadIdx.x & 63;
    int row = blockIdx.x * 4 + wave;

    const float2 ev = *(const float2*)(embed + row * DIM + lane * 2);
    float ss = ev.x * ev.x + ev.y * ev.y;
#pragma unroll
    for (int m = 1; m < 64; m <<= 1) ss += __shfl_xor(ss, m, 64);
    float inv_e = 1.0f / fmaxf(sqrtf(ss), 1e-8f);
    float ex = ev.x * inv_e, ey = ev.y * inv_e;

    const float2 pv = *(const float2*)(proxy + row * DIM + lane * 2);
    float ps = pv.x * pv.x + pv.y * pv.y;
#pragma unroll
    for (int m = 1; m < 64; m <<= 1) ps += __shfl_xor(ps, m, 64);
    float inv_p = 1.0f / fmaxf(sqrtf(ps), 1e-8f);

    float dot = ex * (pv.x * inv_p) + ey * (pv.y * inv_p);
#pragma unroll
    for (int m = 1; m < 64; m <<= 1) dot += __shfl_xor(dot, m, 64);

    ushort2 st; st.x = f2bf(ex * ENSCALE); st.y = f2bf(ey * ENSCALE);
    *(ushort2*)(enb + row * DIM + lane * 2) = st;
    if (lane == 0) e2p[row] = __expf(2.0f * dot);
}

// Kernel 2: fused sim-GEMM + exp + full row sum (tot only; pos separate).
// Each wave owns 64 rows (two 32-row register-resident A groups). Block =
// 4 waves = 256 rows. 2-phase LDS pipeline, 2 tiles (64 cols, 16KB) per
// phase, double-buffered, staged via global_load_lds(16B).
// XOR swizzle both sides: LDS chunk d of col c holds global chunk d^(c&15);
// read applies the same XOR.
// Operand-swapped MFMA: lane cl owns output rows wrbase+cl / wrbase+32+cl;
// acc regs span tile cols: col(reg) = (reg&3) + 4*hi + 8*(reg>>2).
#define DOTILE(buf, tt, cb_tile)                                               \
    {                                                                          \
        const char* base_ = lds + (buf) * 16384 + (tt) * 8192 + cl * 256;      \
        short8 b[8];                                                           \
        _Pragma("unroll")                                                      \
        for (int kk = 0; kk < 8; kk++) {                                       \
            int off = ((kk * 2 + hi) ^ (cl & 15)) * 16;                        \
            b[kk] = *(const short8*)(base_ + off);                             \
        }                                                                      \
        f32x16 c0 = {}, c1 = {};                                               \
        _Pragma("unroll")                                                      \
        for (int kk = 0; kk < 8; kk++) {                                       \
            c0 = __builtin_amdgcn_mfma_f32_32x32x16_bf16(b[kk], rres0[kk], c0, \
                                                         0, 0, 0);             \
            c1 = __builtin_amdgcn_mfma_f32_32x32x16_bf16(b[kk], rres1[kk], c1, \
                                                         0, 0, 0);             \
        }                                                                      \
        const bool d0_ = ((cb_tile) == wrbase);                                \
        const bool d1_ = ((cb_tile) == wrbase + 32);                           \
        _Pragma("unroll")                                                      \
        for (int r = 0; r < 16; r++) {                                         \
            int colr = (r & 3) + 4 * hi + 8 * (r >> 2);                        \
            float s0 = __builtin_amdgcn_exp2f(c0[r]);                          \
            float s1 = __builtin_amdgcn_exp2f(c1[r]);                          \
            s0 = (d0_ && colr == cl) ? 0.f : s0;                               \
            s1 = (d1_ && colr == cl) ? 0.f : s1;                               \
            tot0[r & 3] += s0;                                                 \
            tot1[r & 3] += s1;                                                 \
        }                                                                      \
    }

__global__ __launch_bounds__(256, 2) void simsum_kernel(
    const short* __restrict__ enb, float* __restrict__ ptot)
{
    __shared__ __align__(16) char lds[2 * 16384];
    const int tid = threadIdx.x;
    const int wave = tid >> 6;
    const int lane = tid & 63;
    const int cl = lane & 31;       // output row lane / tile col selector
    const int hi = lane >> 5;       // k-group
    const int wrbase = blockIdx.x * 256 + wave * 64;
    const int cbase0 = blockIdx.y * CHUNKC;

    // staging source indices (fixed per thread)
    const int sc = tid >> 4;                 // 0..15 (col within 16-col half)
    const int sj = (tid & 15) ^ sc;          // pre-swizzled global chunk

    auto stage = [&](int buf, int ph) {
        const int cb = cbase0 + ph * 64;
        char* dbase = lds + buf * 16384 + wave * 1024;   // wave-uniform base
#pragma unroll
        for (int h = 0; h < 4; h++) {
            const short* src = enb + (size_t)(cb + h * 16 + sc) * DIM + sj * 8;
            __builtin_amdgcn_global_load_lds((g_void*)src,
                                             (lds_void*)(dbase + h * 4096),
                                             16, 0, 0);
        }
    };

    // register-resident A: the wave's 64 rows, two 32-row groups
    short8 rres0[8], rres1[8];
    {
        const short* a0 = enb + (size_t)(wrbase + cl) * DIM + hi * 8;
        const short* a1 = enb + (size_t)(wrbase + 32 + cl) * DIM + hi * 8;
#pragma unroll
        for (int kk = 0; kk < 8; kk++) {
            rres0[kk] = *(const short8*)(a0 + kk * 16);
            rres1[kk] = *(const short8*)(a1 + kk * 16);
        }
    }

    float tot0[4] = {0.f, 0.f, 0.f, 0.f};
    float tot1[4] = {0.f, 0.f, 0.f, 0.f};

    int cur = 0;
    stage(0, 0);
    __syncthreads();

#pragma unroll 1
    for (int ph = 0; ph < NPH; ph++) {
        if (ph + 1 < NPH) stage(cur ^ 1, ph + 1);
        const int cb = cbase0 + ph * 64;
        DOTILE(cur, 0, cb);
        DOTILE(cur, 1, cb + 32);
        __syncthreads();          // drains vmcnt(0): next buffer ready
        cur ^= 1;
    }

    float t0 = tot0[0] + tot0[1] + tot0[2] + tot0[3];
    float t1 = tot1[0] + tot1[1] + tot1[2] + tot1[3];
    t0 += __shfl_xor(t0, 32, 64);   // merge the two k-groups (disjoint cols)
    t1 += __shfl_xor(t1, 32, 64);
    if (hi == 0) {
        ptot[blockIdx.y * N_ROWS + wrbase + cl] = t0;
        ptot[blockIdx.y * N_ROWS + wrbase + 32 + cl] = t1;
    }
}

// Kernel 3: positives. One wave per row: ballot-scan labels, lane-parallel
// dot for each same-label j (avg ~8 per row), accumulate exp2(dot_scaled).
__global__ __launch_bounds__(256) void pos_kernel(
    const short* __restrict__ enb, const int* __restrict__ label,
    float* __restrict__ posr)
{
    int wave = threadIdx.x >> 6, lane = threadIdx.x & 63;
    int row = blockIdx.x * 4 + wave;
    int mylab = label[row];

    ushort2 e2 = *(const ushort2*)(enb + (size_t)row * DIM + lane * 2);
    float ei0 = bf2f(e2.x), ei1 = bf2f(e2.y);

    float acc = 0.f;
    for (int ch = 0; ch < N_ROWS / 64; ch++) {
        int j = ch * 64 + lane;
        bool m = (label[j] == mylab) && (j != row);
        unsigned long long mask = __ballot(m);
        while (mask) {
            int jj = ch * 64 + (__ffsll(mask) - 1);
            mask &= mask - 1;
            ushort2 f2 = *(const ushort2*)(enb + (size_t)jj * DIM + lane * 2);
            float d = ei0 * bf2f(f2.x) + ei1 * bf2f(f2.y);
#pragma unroll
            for (int s = 1; s < 64; s <<= 1) d += __shfl_xor(d, s, 64);
            acc += __builtin_amdgcn_exp2f(d);
        }
    }
    if (lane == 0) posr[row] = acc;
}

// Kernel 4: per-row log-ratio, block partial sums.
__global__ __launch_bounds__(256) void loss_partial_kernel(
    const float* __restrict__ e2p, const float* __restrict__ ptot,
    const float* __restrict__ posr, float* __restrict__ pl)
{
    int i = blockIdx.x * 256 + threadIdx.x;
    float tot = 0.f;
#pragma unroll
    for (int c = 0; c < NCHUNK; c++) tot += ptot[c * N_ROWS + i];
    float e = e2p[i];
    float v = __logf((e + posr[i]) / (e + tot));
#pragma unroll
    for (int m = 1; m < 64; m <<= 1) v += __shfl_xor(v, m, 64);
    __shared__ float red[4];
    int wave = threadIdx.x >> 6, lane = threadIdx.x & 63;
    if (lane == 0) red[wave] = v;
    __syncthreads();
    if (threadIdx.x == 0) pl[blockIdx.x] = red[0] + red[1] + red[2] + red[3];
}

// Kernel 5: final sum of 32 partials -> -mean
__global__ void loss_final_kernel(const float* __restrict__ pl,
                                  float* __restrict__ out)
{
    float v = (threadIdx.x < 32) ? pl[threadIdx.x] : 0.f;
#pragma unroll
    for (int m = 1; m < 64; m <<= 1) v += __shfl_xor(v, m, 64);
    if (threadIdx.x == 0) out[0] = -v / (float)N_ROWS;
}

extern "C" void kernel_launch(void* const* d_in, const int* in_sizes, int n_in,
                              void* d_out, int out_size, void* d_ws, size_t ws_size,
                              hipStream_t stream) {
    const float* embed = (const float*)d_in[0];
    const float* proxy = (const float*)d_in[1];
    const int*   label = (const int*)d_in[2];
    float* out = (float*)d_out;

    char* ws = (char*)d_ws;
    short* enb  = (short*)ws;                                   // 2 MB
    float* e2p  = (float*)(ws + 2u * N_ROWS * DIM);             // 32 KB
    float* ptot = e2p + N_ROWS;                                 // 512 KB
    float* posr = ptot + NCHUNK * N_ROWS;                       // 32 KB
    float* pl   = posr + N_ROWS;                                // 128 B

    hipLaunchKernelGGL(norm_kernel, dim3(N_ROWS / 4), dim3(256), 0, stream,
                       embed, proxy, enb, e2p);
    hipLaunchKernelGGL(simsum_kernel, dim3(N_ROWS / 256, NCHUNK), dim3(256), 0, stream,
                       enb, ptot);
    hipLaunchKernelGGL(pos_kernel, dim3(N_ROWS / 4), dim3(256), 0, stream,
                       enb, label, posr);
    hipLaunchKernelGGL(loss_partial_kernel, dim3(N_ROWS / 256), dim3(256), 0, stream,
                       e2p, ptot, posr, pl);
    hipLaunchKernelGGL(loss_final_kernel, dim3(1), dim3(64), 0, stream, pl, out);
}

// Round 6
// 54.868 us; speedup vs baseline: 1.8873x; 1.0522x over previous
//
#include <hip/hip_runtime.h>
#include <hip/hip_bf16.h>

#define N_ROWS 8192
#define DIM    128
#define NCHUNK 16                  // column chunks in sim kernel
#define CHUNKC (N_ROWS / NCHUNK)   // 512 cols per chunk
#define NT     (CHUNKC / 32)       // 16 tiles of 32 cols per chunk
#define NPH    (NT / 2)            // 8 phases, 2 tiles (64 cols) per phase

// sqrt(2*log2(e)) : (s*a)·(s*b) = 2*log2(e)*a·b, so exp2(dot) = exp(2*sim)
#define ENSCALE 1.6986436f

typedef __attribute__((ext_vector_type(8)))  short short8;
typedef __attribute__((ext_vector_type(16))) float f32x16;
typedef __attribute__((address_space(3))) void lds_void;
typedef const __attribute__((address_space(1))) void g_void;

__device__ inline unsigned short f2bf(float f) {
    unsigned u = __float_as_uint(f);
    unsigned r = (u + 0x7FFFu + ((u >> 16) & 1u)) >> 16;
    return (unsigned short)r;
}
__device__ inline float bf2f(unsigned short u) {
    return __uint_as_float(((unsigned)u) << 16);
}
__device__ inline int labof(int4 v, int j) {
    return j == 0 ? v.x : j == 1 ? v.y : j == 2 ? v.z : v.w;
}

// Kernel 1: per-row L2 normalize embed -> bf16 (scaled by ENSCALE), and
// e2p[i] = exp(2*dot(en,pn)) in fp32.
__global__ __launch_bounds__(256) void norm_kernel(
    const float* __restrict__ embed, const float* __restrict__ proxy,
    short* __restrict__ enb, float* __restrict__ e2p)
{
    int wave = threadIdx.x >> 6, lane = threadIdx.x & 63;
    int row = blockIdx.x * 4 + wave;

    const float2 ev = *(const float2*)(embed + row * DIM + lane * 2);
    float ss = ev.x * ev.x + ev.y * ev.y;
#pragma unroll
    for (int m = 1; m < 64; m <<= 1) ss += __shfl_xor(ss, m, 64);
    float inv_e = 1.0f / fmaxf(sqrtf(ss), 1e-8f);
    float ex = ev.x * inv_e, ey = ev.y * inv_e;

    const float2 pv = *(const float2*)(proxy + row * DIM + lane * 2);
    float ps = pv.x * pv.x + pv.y * pv.y;
#pragma unroll
    for (int m = 1; m < 64; m <<= 1) ps += __shfl_xor(ps, m, 64);
    float inv_p = 1.0f / fmaxf(sqrtf(ps), 1e-8f);

    float dot = ex * (pv.x * inv_p) + ey * (pv.y * inv_p);
#pragma unroll
    for (int m = 1; m < 64; m <<= 1) dot += __shfl_xor(dot, m, 64);

    ushort2 st; st.x = f2bf(ex * ENSCALE); st.y = f2bf(ey * ENSCALE);
    *(ushort2*)(enb + row * DIM + lane * 2) = st;
    if (lane == 0) e2p[row] = __expf(2.0f * dot);
}

// Kernel 2: fused sim-GEMM + exp + full row sum (tot only; pos separate).
// Counted-vmcnt pipeline (T3+T4 minimum): 3 LDS buffers of 16KB (2 tiles of
// 32 cols each), stage(ph+2) issued at phase TOP, raw s_barrier + counted
// s_waitcnt vmcnt(4) per phase (never 0 until the last) -> loads span 2 full
// compute phases, queue never drains.
// Buffer safety: stage(ph+2) overwrites buf[(ph-1)%3]; all readers of that
// buffer passed this phase's barrier already.
// XOR swizzle both sides: LDS chunk d of col c holds global chunk d^(c&15);
// read applies the same XOR.
// Operand-swapped MFMA: lane cl owns output rows wrbase+cl / wrbase+32+cl;
// acc regs span tile cols: col(reg) = (reg&3) + 4*hi + 8*(reg>>2).
#define DOTILE(buf, tt, cb_tile)                                               \
    {                                                                          \
        const char* base_ = lds + (buf) * 16384 + (tt) * 8192 + cl * 256;      \
        short8 b[8];                                                           \
        _Pragma("unroll")                                                      \
        for (int kk = 0; kk < 8; kk++) {                                       \
            int off = ((kk * 2 + hi) ^ (cl & 15)) * 16;                        \
            b[kk] = *(const short8*)(base_ + off);                             \
        }                                                                      \
        f32x16 c0 = {}, c1 = {};                                               \
        __builtin_amdgcn_s_setprio(1);                                         \
        _Pragma("unroll")                                                      \
        for (int kk = 0; kk < 8; kk++) {                                       \
            c0 = __builtin_amdgcn_mfma_f32_32x32x16_bf16(b[kk], rres0[kk], c0, \
                                                         0, 0, 0);             \
            c1 = __builtin_amdgcn_mfma_f32_32x32x16_bf16(b[kk], rres1[kk], c1, \
                                                         0, 0, 0);             \
        }                                                                      \
        __builtin_amdgcn_s_setprio(0);                                         \
        const bool d0_ = ((cb_tile) == wrbase);                                \
        const bool d1_ = ((cb_tile) == wrbase + 32);                           \
        _Pragma("unroll")                                                      \
        for (int r = 0; r < 16; r++) {                                         \
            int colr = (r & 3) + 4 * hi + 8 * (r >> 2);                        \
            float s0 = __builtin_amdgcn_exp2f(c0[r]);                          \
            float s1 = __builtin_amdgcn_exp2f(c1[r]);                          \
            s0 = (d0_ && colr == cl) ? 0.f : s0;                               \
            s1 = (d1_ && colr == cl) ? 0.f : s1;                               \
            tot0[r & 3] += s0;                                                 \
            tot1[r & 3] += s1;                                                 \
        }                                                                      \
    }

__global__ __launch_bounds__(256, 2) void simsum_kernel(
    const short* __restrict__ enb, float* __restrict__ ptot)
{
    __shared__ __align__(16) char lds[3 * 16384];
    const int tid = threadIdx.x;
    const int wave = tid >> 6;
    const int lane = tid & 63;
    const int cl = lane & 31;       // output row lane / tile col selector
    const int hi = lane >> 5;       // k-group
    const int wrbase = blockIdx.x * 256 + wave * 64;
    const int cbase0 = blockIdx.y * CHUNKC;

    // staging source indices (fixed per thread)
    const int sc = tid >> 4;                 // 0..15 (col within 16-col half)
    const int sj = (tid & 15) ^ sc;          // pre-swizzled global chunk

    auto stage = [&](int buf, int ph) {
        const int cb = cbase0 + ph * 64;
        char* dbase = lds + buf * 16384 + wave * 1024;   // wave-uniform base
#pragma unroll
        for (int h = 0; h < 4; h++) {
            const short* src = enb + (size_t)(cb + h * 16 + sc) * DIM + sj * 8;
            __builtin_amdgcn_global_load_lds((g_void*)src,
                                             (lds_void*)(dbase + h * 4096),
                                             16, 0, 0);
        }
    };

    // register-resident A: the wave's 64 rows, two 32-row groups
    short8 rres0[8], rres1[8];
    {
        const short* a0 = enb + (size_t)(wrbase + cl) * DIM + hi * 8;
        const short* a1 = enb + (size_t)(wrbase + 32 + cl) * DIM + hi * 8;
#pragma unroll
        for (int kk = 0; kk < 8; kk++) {
            rres0[kk] = *(const short8*)(a0 + kk * 16);
            rres1[kk] = *(const short8*)(a1 + kk * 16);
        }
    }

    float tot0[4] = {0.f, 0.f, 0.f, 0.f};
    float tot1[4] = {0.f, 0.f, 0.f, 0.f};

    stage(0, 0);
    stage(1, 1);

#pragma unroll 1
    for (int ph = 0; ph < NPH; ph++) {
        // own S_ph loads done (leave S_{ph+1}'s 4 in flight); barrier makes
        // it collective.
        if (ph < NPH - 1) {
            asm volatile("s_waitcnt vmcnt(4)" ::: "memory");
        } else {
            asm volatile("s_waitcnt vmcnt(0)" ::: "memory");
        }
        __builtin_amdgcn_s_barrier();
        if (ph + 2 < NPH) stage((ph + 2) % 3, ph + 2);   // issue-early

        const int buf = ph % 3;
        const int cb = cbase0 + ph * 64;
        DOTILE(buf, 0, cb);
        DOTILE(buf, 1, cb + 32);
    }

    float t0 = tot0[0] + tot0[1] + tot0[2] + tot0[3];
    float t1 = tot1[0] + tot1[1] + tot1[2] + tot1[3];
    t0 += __shfl_xor(t0, 32, 64);   // merge the two k-groups (disjoint cols)
    t1 += __shfl_xor(t1, 32, 64);
    if (hi == 0) {
        ptot[blockIdx.y * N_ROWS + wrbase + cl] = t0;
        ptot[blockIdx.y * N_ROWS + wrbase + 32 + cl] = t1;
    }
}

// Kernel 3: positives. One wave per row: int4-vectorized ballot-scan of
// labels (32 dependent iterations instead of 128), lane-parallel dot for
// each same-label j (avg ~8 per row), accumulate exp2(dot_scaled).
__global__ __launch_bounds__(256) void pos_kernel(
    const short* __restrict__ enb, const int* __restrict__ label,
    float* __restrict__ posr)
{
    int wave = threadIdx.x >> 6, lane = threadIdx.x & 63;
    int row = blockIdx.x * 4 + wave;
    int mylab = label[row];

    ushort2 e2 = *(const ushort2*)(enb + (size_t)row * DIM + lane * 2);
    float ei0 = bf2f(e2.x), ei1 = bf2f(e2.y);

    float acc = 0.f;
#pragma unroll 1
    for (int ch = 0; ch < N_ROWS / 256; ch++) {
        int4 lv = *(const int4*)(label + ch * 256 + lane * 4);
#pragma unroll
        for (int q = 0; q < 4; q++) {
            int j = ch * 256 + lane * 4 + q;
            bool m = (labof(lv, q) == mylab) && (j != row);
            unsigned long long mask = __ballot(m);
            while (mask) {
                int jj = ch * 256 + 4 * (__ffsll(mask) - 1) + q;
                mask &= mask - 1;
                ushort2 f2 = *(const ushort2*)(enb + (size_t)jj * DIM + lane * 2);
                float d = ei0 * bf2f(f2.x) + ei1 * bf2f(f2.y);
#pragma unroll
                for (int s = 1; s < 64; s <<= 1) d += __shfl_xor(d, s, 64);
                acc += __builtin_amdgcn_exp2f(d);
            }
        }
    }
    if (lane == 0) posr[row] = acc;
}

// Kernel 4: per-row log-ratio, block partial sums.
__global__ __launch_bounds__(256) void loss_partial_kernel(
    const float* __restrict__ e2p, const float* __restrict__ ptot,
    const float* __restrict__ posr, float* __restrict__ pl)
{
    int i = blockIdx.x * 256 + threadIdx.x;
    float tot = 0.f;
#pragma unroll
    for (int c = 0; c < NCHUNK; c++) tot += ptot[c * N_ROWS + i];
    float e = e2p[i];
    float v = __logf((e + posr[i]) / (e + tot));
#pragma unroll
    for (int m = 1; m < 64; m <<= 1) v += __shfl_xor(v, m, 64);
    __shared__ float red[4];
    int wave = threadIdx.x >> 6, lane = threadIdx.x & 63;
    if (lane == 0) red[wave] = v;
    __syncthreads();
    if (threadIdx.x == 0) pl[blockIdx.x] = red[0] + red[1] + red[2] + red[3];
}

// Kernel 5: final sum of 32 partials -> -mean
__global__ void loss_final_kernel(const float* __restrict__ pl,
                                  float* __restrict__ out)
{
    float v = (threadIdx.x < 32) ? pl[threadIdx.x] : 0.f;
#pragma unroll
    for (int m = 1; m < 64; m <<= 1) v += __shfl_xor(v, m, 64);
    if (threadIdx.x == 0) out[0] = -v / (float)N_ROWS;
}

extern "C" void kernel_launch(void* const* d_in, const int* in_sizes, int n_in,
                              void* d_out, int out_size, void* d_ws, size_t ws_size,
                              hipStream_t stream) {
    const float* embed = (const float*)d_in[0];
    const float* proxy = (const float*)d_in[1];
    const int*   label = (const int*)d_in[2];
    float* out = (float*)d_out;

    char* ws = (char*)d_ws;
    short* enb  = (short*)ws;                                   // 2 MB
    float* e2p  = (float*)(ws + 2u * N_ROWS * DIM);             // 32 KB
    float* ptot = e2p + N_ROWS;                                 // 512 KB
    float* posr = ptot + NCHUNK * N_ROWS;                       // 32 KB
    float* pl   = posr + N_ROWS;                                // 128 B

    hipLaunchKernelGGL(norm_kernel, dim3(N_ROWS / 4), dim3(256), 0, stream,
                       embed, proxy, enb, e2p);
    hipLaunchKernelGGL(simsum_kernel, dim3(N_ROWS / 256, NCHUNK), dim3(256), 0, stream,
                       enb, ptot);
    hipLaunchKernelGGL(pos_kernel, dim3(N_ROWS / 4), dim3(256), 0, stream,
                       enb, label, posr);
    hipLaunchKernelGGL(loss_partial_kernel, dim3(N_ROWS / 256), dim3(256), 0, stream,
                       e2p, ptot, posr, pl);
    hipLaunchKernelGGL(loss_final_kernel, dim3(1), dim3(64), 0, stream, pl, out);
}